// Round 1
// baseline (9664.935 us; speedup 1.0000x reference)
//
#include <hip/hip_runtime.h>
#include <math.h>

// Problem constants (Encoder_4776003633446)
#define S_  1024
#define D_  1024
#define Hh  16
#define DKk 64
#define Bb  2
#define Ff  4096
#define Ll  4

// ---------------------------------------------------------------------------
// Embedding + sinusoidal positional encoding: X[b,s,:] = emb[tok] + pe(s,:)
// ---------------------------------------------------------------------------
__global__ __launch_bounds__(256) void embed_kernel(const int* __restrict__ tokens,
                                                    const float* __restrict__ emb,
                                                    float* __restrict__ X)
{
    const int row = blockIdx.x;            // b*S + s
    const int s   = row & (S_ - 1);
    const int tok = tokens[row];
    const float* e = emb + (size_t)tok * D_;
    float* x = X + (size_t)row * D_;
    const float LN10000 = 9.210340371976184f;
    #pragma unroll
    for (int i = 0; i < 4; ++i) {
        int d = threadIdx.x + 256 * i;
        int half = d >> 1;
        float div = expf(-((float)(2 * half) / (float)D_) * LN10000);
        float ang = (float)s * div;
        float pe = (d & 1) ? cosf(ang) : sinf(ang);
        x[d] = e[d] + pe;
    }
}

// ---------------------------------------------------------------------------
// fp32 tiled GEMM: C[M,N] = A[M,K] @ W[K,N] (+bias) (+exact GELU)
// BM=BN=64, BK=16, 256 threads, 4x4 micro-tile. All dims multiples of 64.
// ---------------------------------------------------------------------------
#define BM 64
#define BN 64
#define BK 16

__global__ __launch_bounds__(256) void gemm_kernel(const float* __restrict__ A,
                                                   const float* __restrict__ W,
                                                   const float* __restrict__ bias,
                                                   float* __restrict__ C,
                                                   int M, int N, int K, int act)
{
    __shared__ float As[BK][BM + 1];   // +1 pad: breaks store conflicts
    __shared__ float Bs[BK][BN];

    const int t  = threadIdx.x;
    const int bm = blockIdx.y * BM;
    const int bn = blockIdx.x * BN;

    const int arow = t >> 2;           // 0..63
    const int acol = (t & 3) << 2;     // 0,4,8,12
    const int brow = t >> 4;           // 0..15
    const int bcol = (t & 15) << 2;    // 0..60

    const int ty = t >> 4;             // 0..15 (row group)
    const int tx = t & 15;             // 0..15 (col group)

    float acc[4][4] = {};

    for (int k0 = 0; k0 < K; k0 += BK) {
        float4 av = *(const float4*)(A + (size_t)(bm + arow) * K + k0 + acol);
        As[acol + 0][arow] = av.x;
        As[acol + 1][arow] = av.y;
        As[acol + 2][arow] = av.z;
        As[acol + 3][arow] = av.w;
        *(float4*)&Bs[brow][bcol] = *(const float4*)(W + (size_t)(k0 + brow) * N + bn + bcol);
        __syncthreads();
        #pragma unroll
        for (int kk = 0; kk < BK; ++kk) {
            float a[4], b[4];
            #pragma unroll
            for (int i = 0; i < 4; ++i) a[i] = As[kk][ty * 4 + i];
            #pragma unroll
            for (int j = 0; j < 4; ++j) b[j] = Bs[kk][tx * 4 + j];
            #pragma unroll
            for (int i = 0; i < 4; ++i)
                #pragma unroll
                for (int j = 0; j < 4; ++j)
                    acc[i][j] += a[i] * b[j];
        }
        __syncthreads();
    }

    #pragma unroll
    for (int i = 0; i < 4; ++i) {
        const int row = bm + ty * 4 + i;
        float4 o;
        float* op = (float*)&o;
        #pragma unroll
        for (int j = 0; j < 4; ++j) {
            const int col = bn + tx * 4 + j;
            float v = acc[i][j];
            if (bias) v += bias[col];
            if (act == 1) v = 0.5f * v * (1.0f + erff(v * 0.70710678118654752f));
            op[j] = v;
        }
        *(float4*)(C + (size_t)row * N + bn + tx * 4) = o;
    }
}

// ---------------------------------------------------------------------------
// Attention: one wave (64 threads) per (b, h, q) row.
// Q/K/V are [B,S,H*64] (natural GEMM output layout).
// ---------------------------------------------------------------------------
__global__ __launch_bounds__(64) void attn_kernel(const float* __restrict__ Q,
                                                  const float* __restrict__ K,
                                                  const float* __restrict__ V,
                                                  const int* __restrict__ tokens,
                                                  float* __restrict__ O)
{
    const int qi = blockIdx.x, h = blockIdx.y, b = blockIdx.z;
    const int lane = threadIdx.x;

    __shared__ float qs[DKk];
    __shared__ float sc[S_];

    const size_t rowq = (size_t)(b * S_ + qi) * D_ + h * DKk;
    qs[lane] = Q[rowq + lane];
    __syncthreads();

    for (int j = lane; j < S_; j += 64) {
        const float* kp = K + (size_t)(b * S_ + j) * D_ + h * DKk;
        float s = 0.f;
        #pragma unroll
        for (int d = 0; d < DKk; ++d) s += qs[d] * kp[d];
        sc[j] = (tokens[b * S_ + j] == 0) ? -1e9f : s * 0.125f;  // 1/sqrt(64)
    }
    __syncthreads();

    float m = -INFINITY;
    for (int j = lane; j < S_; j += 64) m = fmaxf(m, sc[j]);
    #pragma unroll
    for (int o = 32; o > 0; o >>= 1) m = fmaxf(m, __shfl_xor(m, o));

    float sum = 0.f;
    for (int j = lane; j < S_; j += 64) {
        float e = expf(sc[j] - m);
        sc[j] = e;
        sum += e;
    }
    #pragma unroll
    for (int o = 32; o > 0; o >>= 1) sum += __shfl_xor(sum, o);
    __syncthreads();

    const float inv = 1.0f / sum;
    float acc = 0.f;
    for (int j = 0; j < S_; ++j)
        acc += sc[j] * V[(size_t)(b * S_ + j) * D_ + h * DKk + lane];  // coalesced
    O[rowq + lane] = acc * inv;
}

// ---------------------------------------------------------------------------
// Residual add + LayerNorm: out[row,:] = LN(R[row,:] + T[row,:]) * g + b
// One block (256 threads) per row of D_=1024.
// ---------------------------------------------------------------------------
__global__ __launch_bounds__(256) void add_ln_kernel(const float* __restrict__ R,
                                                     const float* __restrict__ T,
                                                     const float* __restrict__ g,
                                                     const float* __restrict__ bta,
                                                     float* __restrict__ out)
{
    const int row = blockIdx.x;
    const int t = threadIdx.x;
    const float* r  = R + (size_t)row * D_;
    const float* tp = T + (size_t)row * D_;

    float v[4];
    float s = 0.f;
    #pragma unroll
    for (int i = 0; i < 4; ++i) {
        int d = t + 256 * i;
        v[i] = r[d] + tp[d];
        s += v[i];
    }

    __shared__ float red[8];
    #pragma unroll
    for (int o = 32; o > 0; o >>= 1) s += __shfl_xor(s, o);
    if ((t & 63) == 0) red[t >> 6] = s;
    __syncthreads();
    const float mean = (red[0] + red[1] + red[2] + red[3]) * (1.0f / D_);

    float vs = 0.f;
    #pragma unroll
    for (int i = 0; i < 4; ++i) { float d = v[i] - mean; vs += d * d; }
    #pragma unroll
    for (int o = 32; o > 0; o >>= 1) vs += __shfl_xor(vs, o);
    if ((t & 63) == 0) red[4 + (t >> 6)] = vs;
    __syncthreads();
    const float var = (red[4] + red[5] + red[6] + red[7]) * (1.0f / D_);
    const float inv = rsqrtf(var + 1e-5f);

    #pragma unroll
    for (int i = 0; i < 4; ++i) {
        int d = t + 256 * i;
        out[(size_t)row * D_ + d] = (v[i] - mean) * inv * g[d] + bta[d];
    }
}

// ---------------------------------------------------------------------------
extern "C" void kernel_launch(void* const* d_in, const int* in_sizes, int n_in,
                              void* d_out, int out_size, void* d_ws, size_t ws_size,
                              hipStream_t stream)
{
    const int*   tokens = (const int*)  d_in[0];
    const float* emb    = (const float*)d_in[1];
    const float* Wq     = (const float*)d_in[2];
    const float* bq     = (const float*)d_in[3];
    const float* Wk     = (const float*)d_in[4];
    const float* bk     = (const float*)d_in[5];
    const float* Wv     = (const float*)d_in[6];
    const float* bv     = (const float*)d_in[7];
    const float* Wo     = (const float*)d_in[8];
    const float* bo     = (const float*)d_in[9];
    const float* ln1g   = (const float*)d_in[10];
    const float* ln1b   = (const float*)d_in[11];
    const float* W1     = (const float*)d_in[12];
    const float* W2     = (const float*)d_in[13];
    const float* ln2g   = (const float*)d_in[14];
    const float* ln2b   = (const float*)d_in[15];

    const int M = Bb * S_;                       // 2048 rows
    const size_t MD = (size_t)M * D_;

    float* X   = (float*)d_ws;
    float* Qb  = X   + MD;
    float* Kb  = Qb  + MD;
    float* Vb  = Kb  + MD;
    float* CTX = Vb  + MD;
    float* T1  = CTX + MD;
    float* HB  = T1  + MD;                       // 2048 x 4096

    embed_kernel<<<M, 256, 0, stream>>>(tokens, emb, X);

    for (int l = 0; l < Ll; ++l) {
        const float* Wq_l = Wq + (size_t)l * D_ * D_;
        const float* Wk_l = Wk + (size_t)l * D_ * D_;
        const float* Wv_l = Wv + (size_t)l * D_ * D_;
        const float* Wo_l = Wo + (size_t)l * D_ * D_;
        const float* W1_l = W1 + (size_t)l * D_ * Ff;
        const float* W2_l = W2 + (size_t)l * Ff * D_;
        const float* bq_l = bq + (size_t)l * D_;
        const float* bk_l = bk + (size_t)l * D_;
        const float* bv_l = bv + (size_t)l * D_;
        const float* bo_l = bo + (size_t)l * D_;
        const float* g1_l = ln1g + (size_t)l * D_;
        const float* b1_l = ln1b + (size_t)l * D_;
        const float* g2_l = ln2g + (size_t)l * D_;
        const float* b2_l = ln2b + (size_t)l * D_;

        dim3 gD(D_ / BN, M / BM);    // N=1024
        dim3 gF(Ff / BN, M / BM);    // N=4096

        gemm_kernel<<<gD, 256, 0, stream>>>(X, Wq_l, bq_l, Qb, M, D_, D_, 0);
        gemm_kernel<<<gD, 256, 0, stream>>>(X, Wk_l, bk_l, Kb, M, D_, D_, 0);
        gemm_kernel<<<gD, 256, 0, stream>>>(X, Wv_l, bv_l, Vb, M, D_, D_, 0);

        attn_kernel<<<dim3(S_, Hh, Bb), 64, 0, stream>>>(Qb, Kb, Vb, tokens, CTX);

        gemm_kernel<<<gD, 256, 0, stream>>>(CTX, Wo_l, bo_l, T1, M, D_, D_, 0);
        add_ln_kernel<<<M, 256, 0, stream>>>(X, T1, g1_l, b1_l, X);

        gemm_kernel<<<gF, 256, 0, stream>>>(X, W1_l, nullptr, HB, M, Ff, D_, 1);
        gemm_kernel<<<gD, 256, 0, stream>>>(HB, W2_l, nullptr, T1, M, D_, Ff, 0);

        float* dst = (l == Ll - 1) ? (float*)d_out : X;
        add_ln_kernel<<<M, 256, 0, stream>>>(X, T1, g2_l, b2_l, dst);
    }
}

// Round 2
// 3969.313 us; speedup vs baseline: 2.4349x; 2.4349x over previous
//
#include <hip/hip_runtime.h>
#include <math.h>

// Problem constants (Encoder_4776003633446)
#define S_  1024
#define D_  1024
#define Hh  16
#define DKk 64
#define Bb  2
#define Ff  4096
#define Ll  4

typedef __bf16 bf16_t;
using bf16x4 = __attribute__((ext_vector_type(4))) __bf16;
using bf16x8 = __attribute__((ext_vector_type(8))) __bf16;
using f32x4  = __attribute__((ext_vector_type(4))) float;

// ---------------------------------------------------------------------------
// Embedding + sinusoidal positional encoding: X[b,s,:] = emb[tok] + pe(s,:)
// ---------------------------------------------------------------------------
__global__ __launch_bounds__(256) void embed_kernel(const int* __restrict__ tokens,
                                                    const float* __restrict__ emb,
                                                    float* __restrict__ X)
{
    const int row = blockIdx.x;            // b*S + s
    const int s   = row & (S_ - 1);
    const int tok = tokens[row];
    const float* e = emb + (size_t)tok * D_;
    float* x = X + (size_t)row * D_;
    const float LN10000 = 9.210340371976184f;
    #pragma unroll
    for (int i = 0; i < 4; ++i) {
        int d = threadIdx.x + 256 * i;
        int half = d >> 1;
        float div = expf(-((float)(2 * half) / (float)D_) * LN10000);
        float ang = (float)s * div;
        float pe = (d & 1) ? cosf(ang) : sinf(ang);
        x[d] = e[d] + pe;
    }
}

// ---------------------------------------------------------------------------
// fp32 tiled GEMM: C[M,N] = A[M,K] @ W[K,N] (+bias) (+exact GELU)
// ---------------------------------------------------------------------------
#define BM 64
#define BN 64
#define BK 16

__global__ __launch_bounds__(256) void gemm_kernel(const float* __restrict__ A,
                                                   const float* __restrict__ W,
                                                   const float* __restrict__ bias,
                                                   float* __restrict__ C,
                                                   int M, int N, int K, int act)
{
    __shared__ float As[BK][BM + 1];
    __shared__ float Bs[BK][BN];

    const int t  = threadIdx.x;
    const int bm = blockIdx.y * BM;
    const int bn = blockIdx.x * BN;

    const int arow = t >> 2;
    const int acol = (t & 3) << 2;
    const int brow = t >> 4;
    const int bcol = (t & 15) << 2;

    const int ty = t >> 4;
    const int tx = t & 15;

    float acc[4][4] = {};

    for (int k0 = 0; k0 < K; k0 += BK) {
        float4 av = *(const float4*)(A + (size_t)(bm + arow) * K + k0 + acol);
        As[acol + 0][arow] = av.x;
        As[acol + 1][arow] = av.y;
        As[acol + 2][arow] = av.z;
        As[acol + 3][arow] = av.w;
        *(float4*)&Bs[brow][bcol] = *(const float4*)(W + (size_t)(k0 + brow) * N + bn + bcol);
        __syncthreads();
        #pragma unroll
        for (int kk = 0; kk < BK; ++kk) {
            float a[4], b[4];
            #pragma unroll
            for (int i = 0; i < 4; ++i) a[i] = As[kk][ty * 4 + i];
            #pragma unroll
            for (int j = 0; j < 4; ++j) b[j] = Bs[kk][tx * 4 + j];
            #pragma unroll
            for (int i = 0; i < 4; ++i)
                #pragma unroll
                for (int j = 0; j < 4; ++j)
                    acc[i][j] += a[i] * b[j];
        }
        __syncthreads();
    }

    #pragma unroll
    for (int i = 0; i < 4; ++i) {
        const int row = bm + ty * 4 + i;
        float4 o;
        float* op = (float*)&o;
        #pragma unroll
        for (int j = 0; j < 4; ++j) {
            const int col = bn + tx * 4 + j;
            float v = acc[i][j];
            if (bias) v += bias[col];
            if (act == 1) v = 0.5f * v * (1.0f + erff(v * 0.70710678118654752f));
            op[j] = v;
        }
        *(float4*)(C + (size_t)row * N + bn + tx * 4) = o;
    }
}

// ---------------------------------------------------------------------------
// fp32 -> bf16 cast (vectorized). n assumed multiple of 1024.
// ---------------------------------------------------------------------------
__global__ __launch_bounds__(256) void cast_bf16_kernel(const float* __restrict__ src,
                                                        bf16_t* __restrict__ dst)
{
    const int i = (blockIdx.x * 256 + threadIdx.x) * 4;
    float4 v = *(const float4*)(src + i);
    bf16x4 o = { (bf16_t)v.x, (bf16_t)v.y, (bf16_t)v.z, (bf16_t)v.w };
    *(bf16x4*)(dst + i) = o;
}

// ---------------------------------------------------------------------------
// Flash attention, bf16 MFMA 16x16x32.
// Grid: (S/64, H, B); block 256 = 4 waves; wave owns 16 query rows.
// LDS row stride 72 bf16 (144 B): 16B-aligned rows, conflict-free b128 frags.
// Layouts (HW-verified, learn_hip m89/m120):
//   A[m=lane&15][k=(lane>>4)*8 + j]   (bf16x8 per frag)
//   B[k=(lane>>4)*8 + j][n=lane&15]
//   C/D[row=(lane>>4)*4 + r][col=lane&15]
// ---------------------------------------------------------------------------
#define AST 72   // LDS row stride in bf16 elements

__global__ __launch_bounds__(256) void attn_mfma_kernel(const bf16_t* __restrict__ Qh,
                                                        const bf16_t* __restrict__ Kh,
                                                        const bf16_t* __restrict__ Vh,
                                                        const int* __restrict__ tokens,
                                                        float* __restrict__ Octx)
{
    const int qt = blockIdx.x;     // query tile (64 rows)
    const int h  = blockIdx.y;
    const int b  = blockIdx.z;
    const int t    = threadIdx.x;
    const int wave = t >> 6;
    const int lane = t & 63;
    const int l15  = lane & 15;
    const int q8   = lane >> 4;

    __shared__ bf16_t Ks[64][AST];        // K tile  [j][d]
    __shared__ bf16_t VsT[64][AST];       // V tile transposed [d][j]
    __shared__ bf16_t Ps[4][16][AST];     // per-wave P round-trip [wave][m][j]

    // Q fragments for this wave's 16 rows (resident all loop)
    const int q0 = qt * 64 + wave * 16;
    bf16x8 qf0, qf1;
    {
        const bf16_t* qp = Qh + ((size_t)(b * S_ + q0 + l15)) * D_ + h * 64 + q8 * 8;
        qf0 = *(const bf16x8*)(qp);
        qf1 = *(const bf16x8*)(qp + 32);
    }

    f32x4 Oacc[4] = {};                    // [d-subtile][r]
    float m_run[4], l_run[4];
    #pragma unroll
    for (int r = 0; r < 4; ++r) { m_run[r] = -INFINITY; l_run[r] = 0.f; }

    for (int jt = 0; jt < S_ / 64; ++jt) {
        __syncthreads();
        // ---- stage K tile: 64 rows x 64 bf16, coalesced 16B chunks
        {
            const bf16_t* kb = Kh + ((size_t)(b * S_ + jt * 64)) * D_ + h * 64;
            #pragma unroll
            for (int u = 0; u < 2; ++u) {
                int id = t + 256 * u;              // 0..511
                int r  = id >> 3;
                int c  = (id & 7) * 8;
                *(uint4*)&Ks[r][c] = *(const uint4*)(kb + (size_t)r * D_ + c);
            }
        }
        // ---- stage V tile transposed: wave w handles d in [w*16, w*16+16)
        {
            const bf16_t* vb = Vh + ((size_t)(b * S_ + jt * 64)) * D_ + h * 64;
            const int j  = lane;                   // 0..63
            const int d0 = wave * 16;
            #pragma unroll
            for (int u = 0; u < 2; ++u) {
                bf16x8 vv = *(const bf16x8*)(vb + (size_t)j * D_ + d0 + u * 8);
                #pragma unroll
                for (int e = 0; e < 8; ++e)
                    VsT[d0 + u * 8 + e][j] = vv[e];   // per-instr: consecutive j -> conflict-free
            }
        }
        __syncthreads();

        // ---- QK^T: scores S[16 x 64] as 4 C-frags
        float sc[4][4];
        #pragma unroll
        for (int nt = 0; nt < 4; ++nt) {
            const bf16_t* kp = &Ks[nt * 16 + l15][q8 * 8];
            bf16x8 b0 = *(const bf16x8*)(kp);
            bf16x8 b1 = *(const bf16x8*)(kp + 32);
            f32x4 acc = {};
            acc = __builtin_amdgcn_mfma_f32_16x16x32_bf16(qf0, b0, acc, 0, 0, 0);
            acc = __builtin_amdgcn_mfma_f32_16x16x32_bf16(qf1, b1, acc, 0, 0, 0);
            const int jg = jt * 64 + nt * 16 + l15;                 // this lane's column
            const float msk = (tokens[b * S_ + jg] == 0) ? -1e9f : 0.f;
            #pragma unroll
            for (int r = 0; r < 4; ++r) sc[nt][r] = acc[r] * 0.125f + msk;
        }

        // ---- online softmax (row = q8*4 + r; 16 lanes of a quad share rows)
        float alpha[4];
        #pragma unroll
        for (int r = 0; r < 4; ++r) {
            float mx = fmaxf(fmaxf(sc[0][r], sc[1][r]), fmaxf(sc[2][r], sc[3][r]));
            #pragma unroll
            for (int o = 1; o < 16; o <<= 1) mx = fmaxf(mx, __shfl_xor(mx, o));
            const float mn = fmaxf(m_run[r], mx);
            alpha[r] = __expf(m_run[r] - mn);
            m_run[r] = mn;
            float s = 0.f;
            #pragma unroll
            for (int nt = 0; nt < 4; ++nt) {
                float p = __expf(sc[nt][r] - mn);
                sc[nt][r] = p;
                s += p;
            }
            #pragma unroll
            for (int o = 1; o < 16; o <<= 1) s += __shfl_xor(s, o);
            l_run[r] = l_run[r] * alpha[r] + s;
        }

        // ---- P: C-layout -> LDS -> A-layout (verified m120 transform)
        #pragma unroll
        for (int nt = 0; nt < 4; ++nt)
            #pragma unroll
            for (int r = 0; r < 4; ++r)
                Ps[wave][q8 * 4 + r][nt * 16 + l15] = (bf16_t)sc[nt][r];

        bf16x8 pf0 = *(const bf16x8*)&Ps[wave][l15][q8 * 8];
        bf16x8 pf1 = *(const bf16x8*)&Ps[wave][l15][32 + q8 * 8];

        // ---- PV: O[16 x 64] += P[16 x 64j] * V[64j x 64d]
        #pragma unroll
        for (int dt = 0; dt < 4; ++dt) {
            #pragma unroll
            for (int r = 0; r < 4; ++r) Oacc[dt][r] *= alpha[r];
            const bf16_t* vp = &VsT[dt * 16 + l15][q8 * 8];
            bf16x8 v0 = *(const bf16x8*)(vp);
            bf16x8 v1 = *(const bf16x8*)(vp + 32);
            Oacc[dt] = __builtin_amdgcn_mfma_f32_16x16x32_bf16(pf0, v0, Oacc[dt], 0, 0, 0);
            Oacc[dt] = __builtin_amdgcn_mfma_f32_16x16x32_bf16(pf1, v1, Oacc[dt], 0, 0, 0);
        }
    }

    // ---- epilogue: normalize and store (fp32 CTX, coalesced 16-lane groups)
    #pragma unroll
    for (int dt = 0; dt < 4; ++dt) {
        #pragma unroll
        for (int r = 0; r < 4; ++r) {
            const int qg = q0 + q8 * 4 + r;
            Octx[((size_t)(b * S_ + qg)) * D_ + h * 64 + dt * 16 + l15] =
                Oacc[dt][r] / l_run[r];
        }
    }
}

// ---------------------------------------------------------------------------
// Residual add + LayerNorm
// ---------------------------------------------------------------------------
__global__ __launch_bounds__(256) void add_ln_kernel(const float* __restrict__ R,
                                                     const float* __restrict__ T,
                                                     const float* __restrict__ g,
                                                     const float* __restrict__ bta,
                                                     float* __restrict__ out)
{
    const int row = blockIdx.x;
    const int t = threadIdx.x;
    const float* r  = R + (size_t)row * D_;
    const float* tp = T + (size_t)row * D_;

    float v[4];
    float s = 0.f;
    #pragma unroll
    for (int i = 0; i < 4; ++i) {
        int d = t + 256 * i;
        v[i] = r[d] + tp[d];
        s += v[i];
    }

    __shared__ float red[8];
    #pragma unroll
    for (int o = 32; o > 0; o >>= 1) s += __shfl_xor(s, o);
    if ((t & 63) == 0) red[t >> 6] = s;
    __syncthreads();
    const float mean = (red[0] + red[1] + red[2] + red[3]) * (1.0f / D_);

    float vs = 0.f;
    #pragma unroll
    for (int i = 0; i < 4; ++i) { float d = v[i] - mean; vs += d * d; }
    #pragma unroll
    for (int o = 32; o > 0; o >>= 1) vs += __shfl_xor(vs, o);
    if ((t & 63) == 0) red[4 + (t >> 6)] = vs;
    __syncthreads();
    const float var = (red[4] + red[5] + red[6] + red[7]) * (1.0f / D_);
    const float inv = rsqrtf(var + 1e-5f);

    #pragma unroll
    for (int i = 0; i < 4; ++i) {
        int d = t + 256 * i;
        out[(size_t)row * D_ + d] = (v[i] - mean) * inv * g[d] + bta[d];
    }
}

// ---------------------------------------------------------------------------
extern "C" void kernel_launch(void* const* d_in, const int* in_sizes, int n_in,
                              void* d_out, int out_size, void* d_ws, size_t ws_size,
                              hipStream_t stream)
{
    const int*   tokens = (const int*)  d_in[0];
    const float* emb    = (const float*)d_in[1];
    const float* Wq     = (const float*)d_in[2];
    const float* bq     = (const float*)d_in[3];
    const float* Wk     = (const float*)d_in[4];
    const float* bk     = (const float*)d_in[5];
    const float* Wv     = (const float*)d_in[6];
    const float* bv     = (const float*)d_in[7];
    const float* Wo     = (const float*)d_in[8];
    const float* bo     = (const float*)d_in[9];
    const float* ln1g   = (const float*)d_in[10];
    const float* ln1b   = (const float*)d_in[11];
    const float* W1     = (const float*)d_in[12];
    const float* W2     = (const float*)d_in[13];
    const float* ln2g   = (const float*)d_in[14];
    const float* ln2b   = (const float*)d_in[15];

    const int M = Bb * S_;                       // 2048 rows
    const size_t MD = (size_t)M * D_;

    float* X   = (float*)d_ws;
    float* Qb  = X   + MD;
    float* Kb  = Qb  + MD;                       // Qb,Kb,Vb contiguous (cast relies on it)
    float* Vb  = Kb  + MD;
    float* CTX = Vb  + MD;
    float* T1  = CTX + MD;
    float* HB  = T1  + MD;                       // 2048 x 4096 (FFN hidden)

    // bf16 Q/K/V live in the (idle-during-attention) HB buffer: 12 MB < 33.5 MB
    bf16_t* Qh = (bf16_t*)HB;
    bf16_t* Kh = Qh + MD;
    bf16_t* Vh = Qh + 2 * MD;

    embed_kernel<<<M, 256, 0, stream>>>(tokens, emb, X);

    for (int l = 0; l < Ll; ++l) {
        const float* Wq_l = Wq + (size_t)l * D_ * D_;
        const float* Wk_l = Wk + (size_t)l * D_ * D_;
        const float* Wv_l = Wv + (size_t)l * D_ * D_;
        const float* Wo_l = Wo + (size_t)l * D_ * D_;
        const float* W1_l = W1 + (size_t)l * D_ * Ff;
        const float* W2_l = W2 + (size_t)l * Ff * D_;
        const float* bq_l = bq + (size_t)l * D_;
        const float* bk_l = bk + (size_t)l * D_;
        const float* bv_l = bv + (size_t)l * D_;
        const float* bo_l = bo + (size_t)l * D_;
        const float* g1_l = ln1g + (size_t)l * D_;
        const float* b1_l = ln1b + (size_t)l * D_;
        const float* g2_l = ln2g + (size_t)l * D_;
        const float* b2_l = ln2b + (size_t)l * D_;

        dim3 gD(D_ / BN, M / BM);    // N=1024
        dim3 gF(Ff / BN, M / BM);    // N=4096

        gemm_kernel<<<gD, 256, 0, stream>>>(X, Wq_l, bq_l, Qb, M, D_, D_, 0);
        gemm_kernel<<<gD, 256, 0, stream>>>(X, Wk_l, bk_l, Kb, M, D_, D_, 0);
        gemm_kernel<<<gD, 256, 0, stream>>>(X, Wv_l, bv_l, Vb, M, D_, D_, 0);

        // cast Q,K,V (contiguous 3*MD floats) -> bf16
        cast_bf16_kernel<<<(int)(3 * MD / 4 / 256), 256, 0, stream>>>(Qb, Qh);

        attn_mfma_kernel<<<dim3(S_ / 64, Hh, Bb), 256, 0, stream>>>(Qh, Kh, Vh, tokens, CTX);

        gemm_kernel<<<gD, 256, 0, stream>>>(CTX, Wo_l, bo_l, T1, M, D_, D_, 0);
        add_ln_kernel<<<M, 256, 0, stream>>>(X, T1, g1_l, b1_l, X);

        gemm_kernel<<<gF, 256, 0, stream>>>(X, W1_l, nullptr, HB, M, Ff, D_, 1);
        gemm_kernel<<<gD, 256, 0, stream>>>(HB, W2_l, nullptr, T1, M, D_, Ff, 0);

        float* dst = (l == Ll - 1) ? (float*)d_out : X;
        add_ln_kernel<<<M, 256, 0, stream>>>(X, T1, g2_l, b2_l, dst);
    }
}

// Round 3
// 1210.080 us; speedup vs baseline: 7.9870x; 3.2802x over previous
//
#include <hip/hip_runtime.h>
#include <math.h>

// Problem constants (Encoder_4776003633446)
#define S_  1024
#define D_  1024
#define Hh  16
#define DKk 64
#define Bb  2
#define Ff  4096
#define Ll  4

typedef __bf16 bf16_t;
using bf16x4 = __attribute__((ext_vector_type(4))) __bf16;
using bf16x8 = __attribute__((ext_vector_type(8))) __bf16;
using f32x4  = __attribute__((ext_vector_type(4))) float;

#define AS1 __attribute__((address_space(1)))
#define AS3 __attribute__((address_space(3)))

// async global->LDS, 16B per lane (dest = wave-uniform base + lane*16)
__device__ __forceinline__ void gld_lds16(const bf16_t* g, bf16_t* l)
{
    __builtin_amdgcn_global_load_lds((AS1 void*)g, (AS3 void*)l, 16, 0, 0);
}

// ---------------------------------------------------------------------------
// Embedding + sinusoidal positional encoding; dual write fp32 + bf16
// ---------------------------------------------------------------------------
__global__ __launch_bounds__(256) void embed_kernel(const int* __restrict__ tokens,
                                                    const float* __restrict__ emb,
                                                    float* __restrict__ X,
                                                    bf16_t* __restrict__ Xh)
{
    const int row = blockIdx.x;            // b*S + s
    const int s   = row & (S_ - 1);
    const int tok = tokens[row];
    const float* e = emb + (size_t)tok * D_;
    const float LN10000 = 9.210340371976184f;
    #pragma unroll
    for (int i = 0; i < 4; ++i) {
        int d = threadIdx.x + 256 * i;
        int half = d >> 1;
        float div = expf(-((float)(2 * half) / (float)D_) * LN10000);
        float ang = (float)s * div;
        float pe = (d & 1) ? cosf(ang) : sinf(ang);
        float v = e[d] + pe;
        X [(size_t)row * D_ + d] = v;
        Xh[(size_t)row * D_ + d] = (bf16_t)v;
    }
}

// ---------------------------------------------------------------------------
// Transpose + cast: in fp32 [K][N] row-major -> out bf16 [N][K] row-major.
// 32x32 tile per block, 256 threads.
// ---------------------------------------------------------------------------
__global__ __launch_bounds__(256) void transpose_cast_kernel(const float* __restrict__ in,
                                                             bf16_t* __restrict__ out,
                                                             int K, int N)
{
    __shared__ float T[32][33];
    const int n0 = blockIdx.x * 32;
    const int k0 = blockIdx.y * 32;
    const int t  = threadIdx.x;
    const int r  = t >> 3;
    const int c  = (t & 7) * 4;

    float4 v = *(const float4*)(in + (size_t)(k0 + r) * N + n0 + c);
    T[r][c + 0] = v.x; T[r][c + 1] = v.y; T[r][c + 2] = v.z; T[r][c + 3] = v.w;
    __syncthreads();

    bf16x4 o = { (bf16_t)T[c + 0][r], (bf16_t)T[c + 1][r],
                 (bf16_t)T[c + 2][r], (bf16_t)T[c + 3][r] };
    *(bf16x4*)(out + (size_t)(n0 + r) * K + k0 + c) = o;
}

// ---------------------------------------------------------------------------
// Concat QKV biases: out[l][0:1024]=bq[l], [1024:2048]=bk[l], [2048:3072]=bv[l]
// ---------------------------------------------------------------------------
__global__ __launch_bounds__(256) void concat_bias_kernel(const float* __restrict__ bq,
                                                          const float* __restrict__ bk,
                                                          const float* __restrict__ bv,
                                                          float* __restrict__ out)
{
    const int id = blockIdx.x * 256 + threadIdx.x;   // < L*3072
    const int l  = id / 3072;
    const int j  = id % 3072;
    float v;
    if (j < 1024)      v = bq[l * 1024 + j];
    else if (j < 2048) v = bk[l * 1024 + j - 1024];
    else               v = bv[l * 1024 + j - 2048];
    out[id] = v;
}

// ---------------------------------------------------------------------------
// bf16 MFMA GEMM (m97 "gemm_bt" structure):
//   C[M,N] = A[M,K] @ Bt[N,K]^T   (M=2048 via grid, K%32==0)
// BM=128, BN template (128 or 64). 256 threads = 4 waves (2x2),
// wave tile 64 x (BN/2), 16x16x32 bf16 MFMA, BK=32,
// global_load_lds width-16 staging, 2-barrier K-loop.
// flags: 1=bias, 2=exact GELU, 4=bf16 output
// ---------------------------------------------------------------------------
template<int BN>
__global__ __launch_bounds__(256) void gemm_bf16_kernel(const bf16_t* __restrict__ A,
                                                        const bf16_t* __restrict__ Bt,
                                                        const float* __restrict__ bias,
                                                        void* __restrict__ Cv,
                                                        int N, int K, int flags)
{
    constexpr int NI = BN / 32;              // per-wave 16-col subtiles
    __shared__ bf16_t As[128 * 32];
    __shared__ bf16_t Bs[BN * 32];

    const int t    = threadIdx.x;
    const int w    = t >> 6;
    const int lane = t & 63;
    const int l15  = lane & 15;
    const int q8   = lane >> 4;
    const int wm   = w >> 1;                 // 0..1
    const int wn   = w & 1;                  // 0..1

    const int bm = blockIdx.y * 128;
    const int bn = blockIdx.x * BN;

    const int lr4 = lane >> 2;               // 0..15 (row within 16-row issue)
    const int lc8 = (lane & 3) * 8;          // 0,8,16,24

    f32x4 acc[4][NI] = {};

    for (int k0 = 0; k0 < K; k0 += 32) {
        // stage A tile 128x32 (8 KB): each wave 2 issues of 16 rows
        #pragma unroll
        for (int u = 0; u < 2; ++u) {
            const int row0 = w * 32 + u * 16;
            gld_lds16(A + (size_t)(bm + row0 + lr4) * K + k0 + lc8,
                      As + row0 * 32);
        }
        // stage B tile BNx32: wave covers BN/4 rows
        #pragma unroll
        for (int u = 0; u < BN / 64; ++u) {
            const int row0 = w * (BN / 4) + u * 16;
            gld_lds16(Bt + (size_t)(bn + row0 + lr4) * K + k0 + lc8,
                      Bs + row0 * 32);
        }
        __syncthreads();   // drains vmcnt(0): DMA'd LDS visible

        bf16x8 af[4], bf[NI];
        #pragma unroll
        for (int mi = 0; mi < 4; ++mi)
            af[mi] = *(const bf16x8*)(As + (wm * 64 + mi * 16 + l15) * 32 + q8 * 8);
        #pragma unroll
        for (int ni = 0; ni < NI; ++ni)
            bf[ni] = *(const bf16x8*)(Bs + (wn * (NI * 16) + ni * 16 + l15) * 32 + q8 * 8);

        #pragma unroll
        for (int mi = 0; mi < 4; ++mi)
            #pragma unroll
            for (int ni = 0; ni < NI; ++ni)
                acc[mi][ni] = __builtin_amdgcn_mfma_f32_16x16x32_bf16(
                                  af[mi], bf[ni], acc[mi][ni], 0, 0, 0);
        __syncthreads();   // all reads done before next stage overwrites
    }

    // epilogue: C/D layout row=q8*4+r, col=l15
    #pragma unroll
    for (int mi = 0; mi < 4; ++mi) {
        #pragma unroll
        for (int ni = 0; ni < NI; ++ni) {
            const int n = bn + wn * (NI * 16) + ni * 16 + l15;
            const float bv_ = (flags & 1) ? bias[n] : 0.f;
            #pragma unroll
            for (int r = 0; r < 4; ++r) {
                const int m = bm + wm * 64 + mi * 16 + q8 * 4 + r;
                float v = acc[mi][ni][r] + bv_;
                if (flags & 2) v = 0.5f * v * (1.0f + erff(v * 0.70710678118654752f));
                if (flags & 4) ((bf16_t*)Cv)[(size_t)m * N + n] = (bf16_t)v;
                else           ((float*) Cv)[(size_t)m * N + n] = v;
            }
        }
    }
}

// ---------------------------------------------------------------------------
// Flash attention, bf16 MFMA 16x16x32. QKV fused input [B*S][3072]
// (Q at +0, K at +1024, V at +2048). Output CTX bf16 [B*S][1024].
// ---------------------------------------------------------------------------
#define AST 72
#define LDQ 3072

__global__ __launch_bounds__(256) void attn_mfma_kernel(const bf16_t* __restrict__ QKV,
                                                        const int* __restrict__ tokens,
                                                        bf16_t* __restrict__ Octx)
{
    const int qt = blockIdx.x;
    const int h  = blockIdx.y;
    const int b  = blockIdx.z;
    const int t    = threadIdx.x;
    const int wave = t >> 6;
    const int lane = t & 63;
    const int l15  = lane & 15;
    const int q8   = lane >> 4;

    __shared__ bf16_t Ks[64][AST];
    __shared__ bf16_t VsT[64][AST];
    __shared__ bf16_t Ps[4][16][AST];

    const bf16_t* Qp = QKV + 0;
    const bf16_t* Kp = QKV + 1024;
    const bf16_t* Vp = QKV + 2048;

    const int q0 = qt * 64 + wave * 16;
    bf16x8 qf0, qf1;
    {
        const bf16_t* qp = Qp + ((size_t)(b * S_ + q0 + l15)) * LDQ + h * 64 + q8 * 8;
        qf0 = *(const bf16x8*)(qp);
        qf1 = *(const bf16x8*)(qp + 32);
    }

    f32x4 Oacc[4] = {};
    float m_run[4], l_run[4];
    #pragma unroll
    for (int r = 0; r < 4; ++r) { m_run[r] = -INFINITY; l_run[r] = 0.f; }

    for (int jt = 0; jt < S_ / 64; ++jt) {
        __syncthreads();
        {
            const bf16_t* kb = Kp + ((size_t)(b * S_ + jt * 64)) * LDQ + h * 64;
            #pragma unroll
            for (int u = 0; u < 2; ++u) {
                int id = t + 256 * u;
                int r  = id >> 3;
                int c  = (id & 7) * 8;
                *(uint4*)&Ks[r][c] = *(const uint4*)(kb + (size_t)r * LDQ + c);
            }
        }
        {
            const bf16_t* vb = Vp + ((size_t)(b * S_ + jt * 64)) * LDQ + h * 64;
            const int j  = lane;
            const int d0 = wave * 16;
            #pragma unroll
            for (int u = 0; u < 2; ++u) {
                bf16x8 vv = *(const bf16x8*)(vb + (size_t)j * LDQ + d0 + u * 8);
                #pragma unroll
                for (int e = 0; e < 8; ++e)
                    VsT[d0 + u * 8 + e][j] = vv[e];
            }
        }
        __syncthreads();

        float sc[4][4];
        #pragma unroll
        for (int nt = 0; nt < 4; ++nt) {
            const bf16_t* kp = &Ks[nt * 16 + l15][q8 * 8];
            bf16x8 b0 = *(const bf16x8*)(kp);
            bf16x8 b1 = *(const bf16x8*)(kp + 32);
            f32x4 a = {};
            a = __builtin_amdgcn_mfma_f32_16x16x32_bf16(qf0, b0, a, 0, 0, 0);
            a = __builtin_amdgcn_mfma_f32_16x16x32_bf16(qf1, b1, a, 0, 0, 0);
            const int jg = jt * 64 + nt * 16 + l15;
            const float msk = (tokens[b * S_ + jg] == 0) ? -1e9f : 0.f;
            #pragma unroll
            for (int r = 0; r < 4; ++r) sc[nt][r] = a[r] * 0.125f + msk;
        }

        float alpha[4];
        #pragma unroll
        for (int r = 0; r < 4; ++r) {
            float mx = fmaxf(fmaxf(sc[0][r], sc[1][r]), fmaxf(sc[2][r], sc[3][r]));
            #pragma unroll
            for (int o = 1; o < 16; o <<= 1) mx = fmaxf(mx, __shfl_xor(mx, o));
            const float mn = fmaxf(m_run[r], mx);
            alpha[r] = __expf(m_run[r] - mn);
            m_run[r] = mn;
            float s = 0.f;
            #pragma unroll
            for (int nt = 0; nt < 4; ++nt) {
                float p = __expf(sc[nt][r] - mn);
                sc[nt][r] = p;
                s += p;
            }
            #pragma unroll
            for (int o = 1; o < 16; o <<= 1) s += __shfl_xor(s, o);
            l_run[r] = l_run[r] * alpha[r] + s;
        }

        #pragma unroll
        for (int nt = 0; nt < 4; ++nt)
            #pragma unroll
            for (int r = 0; r < 4; ++r)
                Ps[wave][q8 * 4 + r][nt * 16 + l15] = (bf16_t)sc[nt][r];

        bf16x8 pf0 = *(const bf16x8*)&Ps[wave][l15][q8 * 8];
        bf16x8 pf1 = *(const bf16x8*)&Ps[wave][l15][32 + q8 * 8];

        #pragma unroll
        for (int dt = 0; dt < 4; ++dt) {
            #pragma unroll
            for (int r = 0; r < 4; ++r) Oacc[dt][r] *= alpha[r];
            const bf16_t* vp = &VsT[dt * 16 + l15][q8 * 8];
            bf16x8 v0 = *(const bf16x8*)(vp);
            bf16x8 v1 = *(const bf16x8*)(vp + 32);
            Oacc[dt] = __builtin_amdgcn_mfma_f32_16x16x32_bf16(pf0, v0, Oacc[dt], 0, 0, 0);
            Oacc[dt] = __builtin_amdgcn_mfma_f32_16x16x32_bf16(pf1, v1, Oacc[dt], 0, 0, 0);
        }
    }

    #pragma unroll
    for (int dt = 0; dt < 4; ++dt) {
        #pragma unroll
        for (int r = 0; r < 4; ++r) {
            const int qg = q0 + q8 * 4 + r;
            Octx[((size_t)(b * S_ + qg)) * D_ + h * 64 + dt * 16 + l15] =
                (bf16_t)(Oacc[dt][r] / l_run[r]);
        }
    }
}

// ---------------------------------------------------------------------------
// Residual add + LayerNorm; dual write fp32 + bf16
// ---------------------------------------------------------------------------
__global__ __launch_bounds__(256) void add_ln_kernel(const float* __restrict__ R,
                                                     const float* __restrict__ T,
                                                     const float* __restrict__ g,
                                                     const float* __restrict__ bta,
                                                     float* __restrict__ out,
                                                     bf16_t* __restrict__ outh)
{
    const int row = blockIdx.x;
    const int t = threadIdx.x;
    const float* r  = R + (size_t)row * D_;
    const float* tp = T + (size_t)row * D_;

    float v[4];
    float s = 0.f;
    #pragma unroll
    for (int i = 0; i < 4; ++i) {
        int d = t + 256 * i;
        v[i] = r[d] + tp[d];
        s += v[i];
    }

    __shared__ float red[8];
    #pragma unroll
    for (int o = 32; o > 0; o >>= 1) s += __shfl_xor(s, o);
    if ((t & 63) == 0) red[t >> 6] = s;
    __syncthreads();
    const float mean = (red[0] + red[1] + red[2] + red[3]) * (1.0f / D_);

    float vs = 0.f;
    #pragma unroll
    for (int i = 0; i < 4; ++i) { float d = v[i] - mean; vs += d * d; }
    #pragma unroll
    for (int o = 32; o > 0; o >>= 1) vs += __shfl_xor(vs, o);
    if ((t & 63) == 0) red[4 + (t >> 6)] = vs;
    __syncthreads();
    const float var = (red[4] + red[5] + red[6] + red[7]) * (1.0f / D_);
    const float inv = rsqrtf(var + 1e-5f);

    #pragma unroll
    for (int i = 0; i < 4; ++i) {
        int d = t + 256 * i;
        float o = (v[i] - mean) * inv * g[d] + bta[d];
        out [(size_t)row * D_ + d] = o;
        outh[(size_t)row * D_ + d] = (bf16_t)o;
    }
}

// ---------------------------------------------------------------------------
extern "C" void kernel_launch(void* const* d_in, const int* in_sizes, int n_in,
                              void* d_out, int out_size, void* d_ws, size_t ws_size,
                              hipStream_t stream)
{
    const int*   tokens = (const int*)  d_in[0];
    const float* emb    = (const float*)d_in[1];
    const float* Wq     = (const float*)d_in[2];
    const float* bq     = (const float*)d_in[3];
    const float* Wk     = (const float*)d_in[4];
    const float* bk     = (const float*)d_in[5];
    const float* Wv     = (const float*)d_in[6];
    const float* bv     = (const float*)d_in[7];
    const float* Wo     = (const float*)d_in[8];
    const float* bo     = (const float*)d_in[9];
    const float* ln1g   = (const float*)d_in[10];
    const float* ln1b   = (const float*)d_in[11];
    const float* W1     = (const float*)d_in[12];
    const float* W2     = (const float*)d_in[13];
    const float* ln2g   = (const float*)d_in[14];
    const float* ln2b   = (const float*)d_in[15];

    const int M = Bb * S_;                       // 2048
    const size_t MD = (size_t)M * D_;

    // ---- workspace layout (~76 MB) ----
    uint8_t* p = (uint8_t*)d_ws;
    float*  X     = (float*)p;           p += MD * 4;                 // 8 MB
    float*  T1    = (float*)p;           p += MD * 4;                 // 8 MB
    bf16_t* Xh    = (bf16_t*)p;          p += MD * 2;                 // 4 MB
    bf16_t* QKVh  = (bf16_t*)p;          p += (size_t)M * 3072 * 2;   // 12 MB
    bf16_t* CTXh  = (bf16_t*)p;          p += MD * 2;                 // 4 MB
    bf16_t* HBh   = (bf16_t*)p;          p += (size_t)M * Ff * 2;     // 16 MB
    bf16_t* WQKVt = (bf16_t*)p;          p += (size_t)3072 * D_ * 2;  // 6 MB
    bf16_t* Wot   = (bf16_t*)p;          p += (size_t)D_ * D_ * 2;    // 2 MB
    bf16_t* W1t   = (bf16_t*)p;          p += (size_t)Ff * D_ * 2;    // 8 MB
    bf16_t* W2t   = (bf16_t*)p;          p += (size_t)D_ * Ff * 2;    // 8 MB
    float*  bqkv  = (float*)p;           p += (size_t)Ll * 3072 * 4;  // 48 KB

    embed_kernel<<<M, 256, 0, stream>>>(tokens, emb, X, Xh);
    concat_bias_kernel<<<Ll * 3072 / 256, 256, 0, stream>>>(bq, bk, bv, bqkv);

    for (int l = 0; l < Ll; ++l) {
        const float* Wq_l = Wq + (size_t)l * D_ * D_;
        const float* Wk_l = Wk + (size_t)l * D_ * D_;
        const float* Wv_l = Wv + (size_t)l * D_ * D_;
        const float* Wo_l = Wo + (size_t)l * D_ * D_;
        const float* W1_l = W1 + (size_t)l * D_ * Ff;
        const float* W2_l = W2 + (size_t)l * Ff * D_;

        // per-layer weight transpose+cast into reused scratch
        dim3 tDD(D_ / 32, D_ / 32);
        transpose_cast_kernel<<<tDD, 256, 0, stream>>>(Wq_l, WQKVt,               D_, D_);
        transpose_cast_kernel<<<tDD, 256, 0, stream>>>(Wk_l, WQKVt + D_ * D_,     D_, D_);
        transpose_cast_kernel<<<tDD, 256, 0, stream>>>(Wv_l, WQKVt + 2 * D_ * D_, D_, D_);
        transpose_cast_kernel<<<tDD, 256, 0, stream>>>(Wo_l, Wot,                 D_, D_);
        transpose_cast_kernel<<<dim3(Ff / 32, D_ / 32), 256, 0, stream>>>(W1_l, W1t, D_, Ff);
        transpose_cast_kernel<<<dim3(D_ / 32, Ff / 32), 256, 0, stream>>>(W2_l, W2t, Ff, D_);

        // QKV fused: [2048,1024] @ [1024,3072] -> bf16 [2048,3072]
        gemm_bf16_kernel<128><<<dim3(3072 / 128, M / 128), 256, 0, stream>>>(
            Xh, WQKVt, bqkv + l * 3072, QKVh, 3072, D_, 1 | 4);

        attn_mfma_kernel<<<dim3(S_ / 64, Hh, Bb), 256, 0, stream>>>(QKVh, tokens, CTXh);

        // Wo: -> fp32 T1 (+bias)
        gemm_bf16_kernel<64><<<dim3(D_ / 64, M / 128), 256, 0, stream>>>(
            CTXh, Wot, bo + (size_t)l * D_, T1, D_, D_, 1);

        add_ln_kernel<<<M, 256, 0, stream>>>(X, T1, ln1g + (size_t)l * D_,
                                             ln1b + (size_t)l * D_, X, Xh);

        // W1 + GELU: -> bf16 HBh
        gemm_bf16_kernel<128><<<dim3(Ff / 128, M / 128), 256, 0, stream>>>(
            Xh, W1t, nullptr, HBh, Ff, D_, 2 | 4);

        // W2: -> fp32 T1
        gemm_bf16_kernel<64><<<dim3(D_ / 64, M / 128), 256, 0, stream>>>(
            HBh, W2t, nullptr, T1, D_, Ff, 0);

        float* dst = (l == Ll - 1) ? (float*)d_out : X;
        add_ln_kernel<<<M, 256, 0, stream>>>(X, T1, ln2g + (size_t)l * D_,
                                             ln2b + (size_t)l * D_, dst, Xh);
    }
}